// Round 8
// baseline (380.693 us; speedup 1.0000x reference)
//
#include <hip/hip_runtime.h>
#include <hip/hip_bf16.h>
#include <float.h>

#define N_CAT   100000
#define N_USERS 50000
#define N_REL   32
#define D       64
#define NEDGE   1600000
#define NNZ     1000000

#define EB_SHIFT 9
#define EB_SIZE  512
#define NBKE     ((N_CAT + EB_SIZE - 1) / EB_SIZE)    // 196 edge buckets
#define UB_SHIFT 8
#define UB_SIZE  256
#define NBKU     ((N_USERS + UB_SIZE - 1) / UB_SIZE)  // 196 user buckets
#define NBK      (NBKE + NBKU)                        // 392

#define T1   4096      // pass1 tile (16 recs/thread @ 256 threads)
#define ECAP 15360     // pass2 edge bucket LDS capacity
#define UCAP 7680      // pass2 user bucket LDS capacity

// bf16 round-to-nearest-even pack/unpack (gather-side precision: ~0.2% rel,
// absmax headroom 0.0625 -> threshold 0.92)
__device__ __forceinline__ unsigned short f2bf(float f) {
    unsigned u = __float_as_uint(f);
    return (unsigned short)((u + 0x7FFF + ((u >> 16) & 1)) >> 16);
}
__device__ __forceinline__ float bf2f(unsigned short h) {
    return __uint_as_float(((unsigned)h) << 16);
}

// ---------------------------------------------------------------------------
// ws: norm2[N_CAT*32] f32 | ccnt[392] | cbase_e[197] | cbase_u[197] |
//     ccur_e[196] | ccur_u[196] | offs_e[100001] | offs_u[50001] |
//     sorted_ta[NEDGE] int | sorted_cv[NNZ] int2 | cath[N_CAT*64] bf16
// total ~41 MB
// ---------------------------------------------------------------------------

// fp32 cat -> bf16 shadow table (halves gather bytes + L2 footprint)
__global__ void cat2bf16_kernel(const float* __restrict__ cat,
                                ushort* __restrict__ cath) {
    int i = blockIdx.x * 256 + threadIdx.x;       // float4 index
    if (i >= N_CAT * 16) return;
    float4 v = ((const float4*)cat)[i];
    ushort4 o;
    o.x = f2bf(v.x); o.y = f2bf(v.y); o.z = f2bf(v.z); o.w = f2bf(v.w);
    ((ushort4*)cath)[i] = o;
}

// norm2[n][r] = sum_d cat[n][d]^2 * W[r][d]^2.  (fp32 inputs; 4 threads/node)
__global__ __launch_bounds__(256) void norm2_kernel(
        const float* __restrict__ cat,
        const float* __restrict__ W,
        float* __restrict__ norm2) {
    __shared__ float4 w2[N_REL * 16];   // squared W, 8 KB
    int t = threadIdx.x;
    const float4* Wv = (const float4*)W;
    for (int i = t; i < N_REL * 16; i += 256) {
        float4 v = Wv[i];
        v.x *= v.x; v.y *= v.y; v.z *= v.z; v.w *= v.w;
        w2[i] = v;
    }
    __syncthreads();

    int node = blockIdx.x * 64 + (t >> 2);
    int q    = t & 3;
    if (node >= N_CAT) return;

    const float4* catv = (const float4*)cat;
    float acc[N_REL];
#pragma unroll
    for (int r = 0; r < N_REL; ++r) acc[r] = 0.f;

#pragma unroll
    for (int c = 0; c < 4; ++c) {
        float4 xv = catv[(size_t)node * 16 + q * 4 + c];
        xv.x *= xv.x; xv.y *= xv.y; xv.z *= xv.z; xv.w *= xv.w;
#pragma unroll
        for (int r = 0; r < N_REL; ++r) {
            float4 wv = w2[r * 16 + q * 4 + c];
            acc[r] += xv.x * wv.x + xv.y * wv.y + xv.z * wv.z + xv.w * wv.w;
        }
    }
#pragma unroll
    for (int r = 0; r < N_REL; ++r) {
        acc[r] += __shfl_xor(acc[r], 1);
        acc[r] += __shfl_xor(acc[r], 2);
    }
    float4* nv = (float4*)norm2;
    size_t base = (size_t)node * 8 + q * 2;
    if (q == 0) {
        nv[base]     = make_float4(acc[0],  acc[1],  acc[2],  acc[3]);
        nv[base + 1] = make_float4(acc[4],  acc[5],  acc[6],  acc[7]);
    } else if (q == 1) {
        nv[base]     = make_float4(acc[8],  acc[9],  acc[10], acc[11]);
        nv[base + 1] = make_float4(acc[12], acc[13], acc[14], acc[15]);
    } else if (q == 2) {
        nv[base]     = make_float4(acc[16], acc[17], acc[18], acc[19]);
        nv[base + 1] = make_float4(acc[20], acc[21], acc[22], acc[23]);
    } else {
        nv[base]     = make_float4(acc[24], acc[25], acc[26], acc[27]);
        nv[base + 1] = make_float4(acc[28], acc[29], acc[30], acc[31]);
    }
}

// per-WG LDS histogram over 392 coarse buckets, single flush
__global__ void coarse_hist_kernel(const int* __restrict__ head,
                                   const int* __restrict__ imr,
                                   int* __restrict__ ccnt) {
    __shared__ int h[NBK];
    int t = threadIdx.x;
    for (int i = t; i < NBK; i += 256) h[i] = 0;
    __syncthreads();
    int stride = gridDim.x * 256;
    for (int i = blockIdx.x * 256 + t; i < NEDGE + NNZ; i += stride) {
        if (i < NEDGE) atomicAdd(&h[head[i] >> EB_SHIFT], 1);
        else           atomicAdd(&h[NBKE + (imr[i - NEDGE] >> UB_SHIFT)], 1);
    }
    __syncthreads();
    for (int i = t; i < NBK; i += 256) if (h[i]) atomicAdd(&ccnt[i], h[i]);
}

// single-WG scan of 392 coarse bins -> bucket bases + cursors + sentinels
__global__ void coarse_scan_kernel(const int* __restrict__ ccnt,
                                   int* __restrict__ cbase_e, int* __restrict__ cbase_u,
                                   int* __restrict__ ccur_e,  int* __restrict__ ccur_u,
                                   int* __restrict__ offs_e,  int* __restrict__ offs_u) {
    __shared__ int sc[256];
    int t = threadIdx.x;
    int c = (t < NBKE) ? ccnt[t] : 0;
    sc[t] = c; __syncthreads();
    for (int off = 1; off < 256; off <<= 1) {
        int v = (t >= off) ? sc[t - off] : 0; __syncthreads();
        sc[t] += v; __syncthreads();
    }
    int excl = sc[t] - c;
    if (t < NBKE) { cbase_e[t] = excl; ccur_e[t] = excl; }
    if (t == NBKE - 1) cbase_e[NBKE] = excl + c;
    __syncthreads();
    c = (t < NBKU) ? ccnt[NBKE + t] : 0;
    sc[t] = c; __syncthreads();
    for (int off = 1; off < 256; off <<= 1) {
        int v = (t >= off) ? sc[t - off] : 0; __syncthreads();
        sc[t] += v; __syncthreads();
    }
    excl = sc[t] - c;
    if (t < NBKU) { cbase_u[t] = excl; ccur_u[t] = excl; }
    if (t == NBKU - 1) cbase_u[NBKU] = excl + c;
    if (t == 0) { offs_e[N_CAT] = NEDGE; offs_u[N_USERS] = NNZ; }
}

// pass1 edges: tile -> LDS count/scan -> ONE global atomic per (tile,bucket)
__global__ __launch_bounds__(256) void pass1_edges_kernel(
        const int* __restrict__ head, const int* __restrict__ tail,
        const int* __restrict__ etype, int* __restrict__ ccur_e,
        int* __restrict__ sorted_ta) {
    __shared__ int cnt[256], loc[256], base[256], sc[256];
    __shared__ int stage[T1];
    __shared__ int gpos[T1];
    int t = threadIdx.x;
    int tile = blockIdx.x * T1;
    cnt[t] = 0;
    __syncthreads();
    int rec[16], bk[16];
#pragma unroll
    for (int k = 0; k < 16; ++k) {
        int i = tile + k * 256 + t;
        if (i < NEDGE) {
            int h = head[i], tl = tail[i], r = etype[i] - 1;
            bk[k]  = h >> EB_SHIFT;
            rec[k] = ((h & (EB_SIZE - 1)) << 22) | (tl << 5) | r;
            atomicAdd(&cnt[bk[k]], 1);
        } else bk[k] = -1;
    }
    __syncthreads();
    int c = cnt[t];
    sc[t] = c; __syncthreads();
    for (int off = 1; off < 256; off <<= 1) {
        int v = (t >= off) ? sc[t - off] : 0; __syncthreads();
        sc[t] += v; __syncthreads();
    }
    loc[t] = sc[t] - c;
    if (t < NBKE && c > 0) base[t] = atomicAdd(&ccur_e[t], c);
    __syncthreads();
    cnt[t] = loc[t];
    __syncthreads();
#pragma unroll
    for (int k = 0; k < 16; ++k) {
        if (bk[k] >= 0) {
            int p = atomicAdd(&cnt[bk[k]], 1);
            stage[p] = rec[k];
            gpos[p]  = base[bk[k]] + (p - loc[bk[k]]);
        }
    }
    __syncthreads();
    int nv = min(T1, NEDGE - tile);
    for (int i = t; i < nv; i += 256) sorted_ta[gpos[i]] = stage[i];
}

__global__ __launch_bounds__(256) void pass1_users_kernel(
        const int* __restrict__ imr, const int* __restrict__ imc,
        const float* __restrict__ imv, int* __restrict__ ccur_u,
        int2* __restrict__ sorted_cv) {
    __shared__ int cnt[256], loc[256], base[256], sc[256];
    __shared__ int2 stage[T1];
    __shared__ int gpos[T1];
    int t = threadIdx.x;
    int tile = blockIdx.x * T1;
    cnt[t] = 0;
    __syncthreads();
    int2 rec[16]; int bk[16];
#pragma unroll
    for (int k = 0; k < 16; ++k) {
        int i = tile + k * 256 + t;
        if (i < NNZ) {
            int rr = imr[i];
            bk[k]  = rr >> UB_SHIFT;
            rec[k] = make_int2(((rr & (UB_SIZE - 1)) << 17) | imc[i],
                               __float_as_int(imv[i]));
            atomicAdd(&cnt[bk[k]], 1);
        } else bk[k] = -1;
    }
    __syncthreads();
    int c = cnt[t];
    sc[t] = c; __syncthreads();
    for (int off = 1; off < 256; off <<= 1) {
        int v = (t >= off) ? sc[t - off] : 0; __syncthreads();
        sc[t] += v; __syncthreads();
    }
    loc[t] = sc[t] - c;
    if (t < NBKU && c > 0) base[t] = atomicAdd(&ccur_u[t], c);
    __syncthreads();
    cnt[t] = loc[t];
    __syncthreads();
#pragma unroll
    for (int k = 0; k < 16; ++k) {
        if (bk[k] >= 0) {
            int p = atomicAdd(&cnt[bk[k]], 1);
            stage[p] = rec[k];
            gpos[p]  = base[bk[k]] + (p - loc[bk[k]]);
        }
    }
    __syncthreads();
    int nv = min(T1, NNZ - tile);
    for (int i = t; i < nv; i += 256) sorted_cv[gpos[i]] = stage[i];
}

// pass2: one WG per coarse bucket; fine counting-sort in LDS; writes fine offs
__global__ __launch_bounds__(256) void pass2_kernel(
        const int* __restrict__ cbase_e, const int* __restrict__ cbase_u,
        int* __restrict__ offs_e, int* __restrict__ offs_u,
        int* __restrict__ sorted_ta, int2* __restrict__ sorted_cv) {
    __shared__ int lds[UCAP * 2];        // 60 KB
    __shared__ int fh[EB_SIZE + 1];
    __shared__ int sc[256];
    int t = threadIdx.x;
    int b = blockIdx.x;
    if (b < NBKE) {
        int h0 = b << EB_SHIFT;
        int start = cbase_e[b], end = cbase_e[b + 1];
        int n = min(end - start, ECAP);
        for (int i = t; i < n; i += 256) lds[i] = sorted_ta[start + i];
        fh[2 * t] = 0; fh[2 * t + 1] = 0;
        __syncthreads();
        for (int i = t; i < n; i += 256) atomicAdd(&fh[lds[i] >> 22], 1);
        __syncthreads();
        int a = fh[2 * t], b2 = fh[2 * t + 1];
        sc[t] = a + b2; __syncthreads();
        for (int off = 1; off < 256; off <<= 1) {
            int v = (t >= off) ? sc[t - off] : 0; __syncthreads();
            sc[t] += v; __syncthreads();
        }
        int pe = sc[t] - (a + b2);
        int lim = min(EB_SIZE, N_CAT - h0);
        if (2 * t     < lim) offs_e[h0 + 2 * t]     = start + pe;
        if (2 * t + 1 < lim) offs_e[h0 + 2 * t + 1] = start + pe + a;
        fh[2 * t] = pe; fh[2 * t + 1] = pe + a;
        __syncthreads();
        for (int i = t; i < n; i += 256) {
            int rec = lds[i];
            int p = atomicAdd(&fh[rec >> 22], 1);
            sorted_ta[start + p] = rec & 0x3FFFFF;     // (tail<<5)|rel
        }
    } else {
        int k = b - NBKE;
        int u0 = k << UB_SHIFT;
        int start = cbase_u[k], end = cbase_u[k + 1];
        int n = min(end - start, UCAP);
        int2* lds2 = (int2*)lds;
        for (int i = t; i < n; i += 256) lds2[i] = sorted_cv[start + i];
        fh[t] = 0;
        __syncthreads();
        for (int i = t; i < n; i += 256) atomicAdd(&fh[lds2[i].x >> 17], 1);
        __syncthreads();
        int c = fh[t];
        sc[t] = c; __syncthreads();
        for (int off = 1; off < 256; off <<= 1) {
            int v = (t >= off) ? sc[t - off] : 0; __syncthreads();
            sc[t] += v; __syncthreads();
        }
        int excl = sc[t] - c;
        int lim = min(UB_SIZE, N_USERS - u0);
        if (t < lim) offs_u[u0 + t] = start + excl;
        fh[t] = excl;
        __syncthreads();
        for (int i = t; i < n; i += 256) {
            int2 rec = lds2[i];
            int p = atomicAdd(&fh[rec.x >> 17], 1);
            sorted_cv[start + p] = make_int2(rec.x & 0x1FFFF, rec.y);
        }
    }
}

// one wave per head; bf16 gathers from cath; fast path deg<=64
__global__ void cat_agg_sorted_kernel(const int* __restrict__ offs_e,
                                      const int* __restrict__ sorted_ta,
                                      const float* __restrict__ norm2,
                                      const ushort* __restrict__ cath,
                                      const float* __restrict__ W,
                                      float* __restrict__ cat_agg) {
    int wv   = threadIdx.x >> 6;
    int lane = threadIdx.x & 63;
    int h = blockIdx.x * 4 + wv;
    int start = offs_e[h];
    int end   = offs_e[h + 1];
    int deg   = end - start;

    float a0 = 0.f, a1 = 0.f, a2 = 0.f, a3 = 0.f;

    if (deg <= 64) {
        int   rec = 0;
        float att = -FLT_MAX;
        if (lane < deg) {
            rec = sorted_ta[start + lane];
            int tt = rec >> 5, r = rec & 31;
            att = norm2[h * N_REL + r] * norm2[(size_t)tt * N_REL + r];
        }
        float m = att;
#pragma unroll
        for (int off = 32; off > 0; off >>= 1) m = fmaxf(m, __shfl_xor(m, off));
        float ex = (lane < deg) ? __expf(att - m) : 0.f;
        float ssum = ex;
#pragma unroll
        for (int off = 32; off > 0; off >>= 1) ssum += __shfl_xor(ssum, off);
        float w = (deg > 0) ? ex / ssum : 0.f;

        int j = 0;
        for (; j + 4 <= deg; j += 4) {
            int   tr0 = __shfl(rec, j + 0), tr1 = __shfl(rec, j + 1);
            int   tr2 = __shfl(rec, j + 2), tr3 = __shfl(rec, j + 3);
            float w0  = __shfl(w,   j + 0), w1  = __shfl(w,   j + 1);
            float w2  = __shfl(w,   j + 2), w3  = __shfl(w,   j + 3);
            a0 += w0 * bf2f(cath[(size_t)(tr0 >> 5) * D + lane]) * W[(tr0 & 31) * D + lane];
            a1 += w1 * bf2f(cath[(size_t)(tr1 >> 5) * D + lane]) * W[(tr1 & 31) * D + lane];
            a2 += w2 * bf2f(cath[(size_t)(tr2 >> 5) * D + lane]) * W[(tr2 & 31) * D + lane];
            a3 += w3 * bf2f(cath[(size_t)(tr3 >> 5) * D + lane]) * W[(tr3 & 31) * D + lane];
        }
        for (; j < deg; ++j) {
            int   tr = __shfl(rec, j);
            float ww = __shfl(w,   j);
            a0 += ww * bf2f(cath[(size_t)(tr >> 5) * D + lane]) * W[(tr & 31) * D + lane];
        }
    } else {
        float m = -FLT_MAX;
        for (int j = lane; j < deg; j += 64) {
            int rec = sorted_ta[start + j];
            int tt = rec >> 5, r = rec & 31;
            m = fmaxf(m, norm2[h * N_REL + r] * norm2[(size_t)tt * N_REL + r]);
        }
#pragma unroll
        for (int off = 32; off > 0; off >>= 1) m = fmaxf(m, __shfl_xor(m, off));
        float ssum = 0.f;
        for (int j = lane; j < deg; j += 64) {
            int rec = sorted_ta[start + j];
            int tt = rec >> 5, r = rec & 31;
            ssum += __expf(norm2[h * N_REL + r] * norm2[(size_t)tt * N_REL + r] - m);
        }
#pragma unroll
        for (int off = 32; off > 0; off >>= 1) ssum += __shfl_xor(ssum, off);
        float inv = 1.f / ssum;
        for (int j0 = 0; j0 < deg; j0 += 64) {
            int n = min(64, deg - j0);
            int   rec = 0;
            float w   = 0.f;
            if (lane < n) {
                rec = sorted_ta[start + j0 + lane];
                int tt = rec >> 5, r = rec & 31;
                w = __expf(norm2[h * N_REL + r] * norm2[(size_t)tt * N_REL + r] - m) * inv;
            }
            for (int j = 0; j < n; ++j) {
                int   tr = __shfl(rec, j);
                float ww = __shfl(w,   j);
                a0 += ww * bf2f(cath[(size_t)(tr >> 5) * D + lane]) * W[(tr & 31) * D + lane];
            }
        }
    }
    cat_agg[(size_t)h * D + lane] = (a0 + a1) + (a2 + a3);
}

// one wave per user: bf16 SpMM row (8 gathers in flight) + relation gating
__global__ void spmm_user_kernel(const int* __restrict__ offs_u,
                                 const int2* __restrict__ sorted_cv,
                                 const ushort* __restrict__ cath,
                                 const float* __restrict__ uemb,
                                 const float* __restrict__ W,
                                 float* __restrict__ uagg) {
    __shared__ float s_user[4][D];
    __shared__ float s_score[4][N_REL];
    int wv   = threadIdx.x >> 6;
    int lane = threadIdx.x & 63;
    int u = blockIdx.x * 4 + wv;
    int start = offs_u[u];
    int end   = offs_u[u + 1];
    int deg   = end - start;

    float a0 = 0.f, a1 = 0.f, a2 = 0.f, a3 = 0.f;
    float a4 = 0.f, a5 = 0.f, a6 = 0.f, a7 = 0.f;
    for (int j0 = 0; j0 < deg; j0 += 64) {
        int n = min(64, deg - j0);
        int   my_c = 0;
        float my_v = 0.f;
        if (lane < n) {
            int2 cv = sorted_cv[start + j0 + lane];
            my_c = cv.x;
            my_v = __int_as_float(cv.y);
        }
        int j = 0;
        for (; j + 8 <= n; j += 8) {
            int   c0 = __shfl(my_c, j + 0), c1 = __shfl(my_c, j + 1);
            int   c2 = __shfl(my_c, j + 2), c3 = __shfl(my_c, j + 3);
            int   c4 = __shfl(my_c, j + 4), c5 = __shfl(my_c, j + 5);
            int   c6 = __shfl(my_c, j + 6), c7 = __shfl(my_c, j + 7);
            float v0 = __shfl(my_v, j + 0), v1 = __shfl(my_v, j + 1);
            float v2 = __shfl(my_v, j + 2), v3 = __shfl(my_v, j + 3);
            float v4 = __shfl(my_v, j + 4), v5 = __shfl(my_v, j + 5);
            float v6 = __shfl(my_v, j + 6), v7 = __shfl(my_v, j + 7);
            a0 += v0 * bf2f(cath[(size_t)c0 * D + lane]);
            a1 += v1 * bf2f(cath[(size_t)c1 * D + lane]);
            a2 += v2 * bf2f(cath[(size_t)c2 * D + lane]);
            a3 += v3 * bf2f(cath[(size_t)c3 * D + lane]);
            a4 += v4 * bf2f(cath[(size_t)c4 * D + lane]);
            a5 += v5 * bf2f(cath[(size_t)c5 * D + lane]);
            a6 += v6 * bf2f(cath[(size_t)c6 * D + lane]);
            a7 += v7 * bf2f(cath[(size_t)c7 * D + lane]);
        }
        for (; j < n; ++j) {
            int   cc = __shfl(my_c, j);
            float vv = __shfl(my_v, j);
            a0 += vv * bf2f(cath[(size_t)cc * D + lane]);
        }
    }
    float acc = ((a0 + a1) + (a2 + a3)) + ((a4 + a5) + (a6 + a7));

    s_user[wv][lane] = uemb[(size_t)u * D + lane];
    __syncthreads();

    if (lane < N_REL) {
        float dot = 0.f;
#pragma unroll
        for (int d = 0; d < D; ++d) dot += s_user[wv][d] * W[lane * D + d];
        float mm = dot;
#pragma unroll
        for (int off = 16; off > 0; off >>= 1) mm = fmaxf(mm, __shfl_xor(mm, off));
        float ex = __expf(dot - mm);
        float sm = ex;
#pragma unroll
        for (int off = 16; off > 0; off >>= 1) sm += __shfl_xor(sm, off);
        s_score[wv][lane] = ex / sm;
    }
    __syncthreads();

    float proj = 0.f;
#pragma unroll
    for (int r = 0; r < N_REL; ++r) proj += s_score[wv][r] * W[r * D + lane];

    uagg[(size_t)u * D + lane] = acc * (1.f + proj);
}

extern "C" void kernel_launch(void* const* d_in, const int* in_sizes, int n_in,
                              void* d_out, int out_size, void* d_ws, size_t ws_size,
                              hipStream_t stream) {
    const float* cat   = (const float*)d_in[0];
    const float* uemb  = (const float*)d_in[1];
    const int*   eidx  = (const int*)d_in[2];
    const int*   etype = (const int*)d_in[3];
    const int*   imr   = (const int*)d_in[4];
    const int*   imc   = (const int*)d_in[5];
    const float* imv   = (const float*)d_in[6];
    const float* W     = (const float*)d_in[7];
    const int* head = eidx;
    const int* tail = eidx + NEDGE;

    float* out     = (float*)d_out;
    float* cat_agg = out;                         // [N_CAT, D]
    float* uagg    = out + (size_t)N_CAT * D;     // [N_USERS, D]

    float* norm2   = (float*)d_ws;
    int*   ccnt    = (int*)(norm2 + (size_t)N_CAT * N_REL);
    int*   cbase_e = ccnt + NBK;
    int*   cbase_u = cbase_e + NBKE + 1;
    int*   ccur_e  = cbase_u + NBKU + 1;
    int*   ccur_u  = ccur_e + NBKE;
    int*   offs_e  = ccur_u + NBKU;
    int*   offs_u  = offs_e + N_CAT + 1;
    int*   sorted_ta = offs_u + N_USERS + 1;
    int2*  sorted_cv = (int2*)(sorted_ta + NEDGE);
    ushort* cath   = (ushort*)(sorted_cv + NNZ);   // bf16 shadow of cat, 12.8 MB

    hipMemsetAsync(ccnt, 0, (size_t)NBK * sizeof(int), stream);

    cat2bf16_kernel<<<(N_CAT * 16 + 255) / 256, 256, 0, stream>>>(cat, cath);
    coarse_hist_kernel<<<512, 256, 0, stream>>>(head, imr, ccnt);
    coarse_scan_kernel<<<1, 256, 0, stream>>>(ccnt, cbase_e, cbase_u,
                                              ccur_e, ccur_u, offs_e, offs_u);
    pass1_edges_kernel<<<(NEDGE + T1 - 1) / T1, 256, 0, stream>>>(
        head, tail, etype, ccur_e, sorted_ta);
    pass1_users_kernel<<<(NNZ + T1 - 1) / T1, 256, 0, stream>>>(
        imr, imc, imv, ccur_u, sorted_cv);
    pass2_kernel<<<NBK, 256, 0, stream>>>(cbase_e, cbase_u, offs_e, offs_u,
                                          sorted_ta, sorted_cv);
    norm2_kernel<<<(N_CAT + 63) / 64, 256, 0, stream>>>(cat, W, norm2);
    cat_agg_sorted_kernel<<<N_CAT / 4, 256, 0, stream>>>(offs_e, sorted_ta, norm2, cath, W, cat_agg);
    spmm_user_kernel<<<N_USERS / 4, 256, 0, stream>>>(offs_u, sorted_cv, cath, uemb, W, uagg);
}